// Round 1
// baseline (6836.761 us; speedup 1.0000x reference)
//
#include <hip/hip_runtime.h>
#include <stdint.h>

// ---------------------------------------------------------------------------
// DecoderLSTM: B=32, S=128, H=1024, L=2, V=32000, teacher forcing (tf=1)
//
// Plan:
//   1. Convert emb/w_ih/w_hh -> bf16 (ws), bsum = b_ih+b_hh, h/c init.
//   2. Embed all tokens -> x_seq bf16 [S*B=4096][1024]  (rows m = t*32+b)
//   3. Zx0 = x_seq @ w_ih[0]^T + bsum0  (MFMA GEMM, f32 out, lives in d_out)
//   4. 128 steps x 2 layers: z = base + h @ W^T (+ h2 @ W2^T); gates; h,c.
//      h kept bf16 (ping-pong), c kept f32 (in-place, per-thread RMW).
//      Layer1 h also written to outbuf rows m = b*128+t.
//   5. out[b,s,v] = outbuf @ emb_bf^T (MFMA GEMM, M=4096, N=32000, K=1024)
// ---------------------------------------------------------------------------

typedef __attribute__((ext_vector_type(8))) short short8;
typedef __attribute__((ext_vector_type(4))) float f32x4;

#define MFMA16(a, b, c) __builtin_amdgcn_mfma_f32_16x16x32_bf16((a), (b), (c), 0, 0, 0)

__device__ __forceinline__ unsigned short f2bf(float f) {
  union { float f; unsigned int u; } v; v.f = f;
  unsigned int u = v.u;
  return (unsigned short)((u + 0x7fffu + ((u >> 16) & 1u)) >> 16);
}

// ---- conversion / small kernels -------------------------------------------

__global__ void cvt_bf16_k(const float* __restrict__ s, unsigned short* __restrict__ d, int n4) {
  int i = blockIdx.x * blockDim.x + threadIdx.x;
  int st = gridDim.x * blockDim.x;
  for (; i < n4; i += st) {
    float4 v = ((const float4*)s)[i];
    ushort4 o;
    o.x = f2bf(v.x); o.y = f2bf(v.y); o.z = f2bf(v.z); o.w = f2bf(v.w);
    ((ushort4*)d)[i] = o;
  }
}

__global__ void copy_f32_k(const float* __restrict__ s, float* __restrict__ d, int n4) {
  int i = blockIdx.x * blockDim.x + threadIdx.x;
  int st = gridDim.x * blockDim.x;
  for (; i < n4; i += st) ((float4*)d)[i] = ((const float4*)s)[i];
}

__global__ void bias_sum_k(const float* __restrict__ a, const float* __restrict__ b,
                           float* __restrict__ o, int n) {
  int i = blockIdx.x * blockDim.x + threadIdx.x;
  if (i < n) o[i] = a[i] + b[i];
}

// x_seq[t*32+b][0:1024] = bf16(emb[token(t,b)])
__global__ void embed_k(const int* __restrict__ x, const int* __restrict__ tgt,
                        const float* __restrict__ emb, unsigned short* __restrict__ xseq) {
  int row = blockIdx.x;          // t*32 + b
  int t = row >> 5, b = row & 31;
  int tok = (t == 0) ? x[b] : tgt[b * 128 + t];
  const float4* e = (const float4*)(emb + (size_t)tok * 1024);
  ushort4* o = (ushort4*)(xseq + (size_t)row * 1024);
  int i = threadIdx.x;           // 256 threads, 256 float4 per row
  float4 v = e[i];
  ushort4 u;
  u.x = f2bf(v.x); u.y = f2bf(v.y); u.z = f2bf(v.z); u.w = f2bf(v.w);
  o[i] = u;
}

// ---- bf16 MFMA GEMM: C[M][N] = A[M][K] * B[N][K]^T (+bias[col]) -----------
// BM=BN=128, BK=64, 256 threads (4 waves, 2x2 of 64x64), K=1024 fixed.
// LDS tiles XOR-chunk-swizzled: LDS[row][c^(row&7)] = G[row][c]  (chunks=16B)

__global__ __launch_bounds__(256, 2) void gemm_bf16_k(
    const unsigned short* __restrict__ A,   // [M][1024]
    const unsigned short* __restrict__ B,   // [N][1024]
    float* __restrict__ C,                  // [M][N]
    const float* __restrict__ bias,         // [N] or nullptr
    int N) {
  __shared__ __align__(16) unsigned short As[128 * 64];
  __shared__ __align__(16) unsigned short Bs[128 * 64];
  const int tid = threadIdx.x;
  const int lane = tid & 63;
  const int w = tid >> 6;
  const int wm = w >> 1, wn = w & 1;
  const int mBase = blockIdx.y * 128;
  const int nBase = blockIdx.x * 128;
  const int lr = lane & 15, lk = lane >> 4;
  const int K = 1024;

  f32x4 acc[4][4];
#pragma unroll
  for (int i = 0; i < 4; ++i)
#pragma unroll
    for (int j = 0; j < 4; ++j) acc[i][j] = (f32x4){0.f, 0.f, 0.f, 0.f};

  for (int kt = 0; kt < K / 64; ++kt) {
    int4 va[4], vb[4];
#pragma unroll
    for (int r = 0; r < 4; ++r) {
      int q = r * 256 + tid;         // chunk id 0..1023 (16B chunks)
      int row = q >> 3, c = q & 7;   // linear global read (coalesced)
      va[r] = *(const int4*)(A + (size_t)(mBase + row) * K + kt * 64 + c * 8);
      vb[r] = *(const int4*)(B + (size_t)(nBase + row) * K + kt * 64 + c * 8);
    }
    __syncthreads();   // previous iteration's LDS reads complete
#pragma unroll
    for (int r = 0; r < 4; ++r) {
      int q = r * 256 + tid;
      int row = q >> 3, c = q & 7;
      int cs = c ^ (row & 7);
      *(int4*)&As[row * 64 + cs * 8] = va[r];
      *(int4*)&Bs[row * 64 + cs * 8] = vb[r];
    }
    __syncthreads();
#pragma unroll
    for (int ks = 0; ks < 2; ++ks) {
      short8 a[4], b[4];
#pragma unroll
      for (int mf = 0; mf < 4; ++mf) {
        int row = wm * 64 + mf * 16 + lr;
        int cc = (ks * 4 + lk) ^ (row & 7);
        a[mf] = *(const short8*)&As[row * 64 + cc * 8];
      }
#pragma unroll
      for (int nf = 0; nf < 4; ++nf) {
        int row = wn * 64 + nf * 16 + lr;
        int cc = (ks * 4 + lk) ^ (row & 7);
        b[nf] = *(const short8*)&Bs[row * 64 + cc * 8];
      }
#pragma unroll
      for (int mf = 0; mf < 4; ++mf)
#pragma unroll
        for (int nf = 0; nf < 4; ++nf)
          acc[mf][nf] = MFMA16(a[mf], b[nf], acc[mf][nf]);
    }
  }

  // epilogue: D row=(lane>>4)*4+reg, col=lane&15
#pragma unroll
  for (int mf = 0; mf < 4; ++mf) {
#pragma unroll
    for (int nf = 0; nf < 4; ++nf) {
      int col = nBase + wn * 64 + nf * 16 + lr;
      float bv = bias ? bias[col] : 0.f;
#pragma unroll
      for (int i = 0; i < 4; ++i) {
        int row = mBase + wm * 64 + mf * 16 + lk * 4 + i;
        C[(size_t)row * N + col] = acc[mf][nf][i] + bv;
      }
    }
  }
}

// ---- LSTM step: z[b][j] = base/bias + hA@W1^T (+ hB@W2^T); gates ----------
// grid 64 (k-slices of 16), 256 threads = 4 waves (one gate each).
template <int NMAT, int WOUT>
__global__ __launch_bounds__(256) void lstm_step_k(
    const unsigned short* __restrict__ hA, const unsigned short* __restrict__ W1,
    const unsigned short* __restrict__ hB, const unsigned short* __restrict__ W2,
    const float* __restrict__ base,   // [32][4096] (Zx0 block) or nullptr
    const float* __restrict__ bias,   // [4096] or nullptr
    float* __restrict__ c,            // [32][1024] in-place
    unsigned short* __restrict__ h_out,  // [32][1024] bf16
    unsigned short* __restrict__ out_t)  // outbuf + t*1024 (row stride 131072) or nullptr
{
  const int tid = threadIdx.x;
  const int lane = tid & 63;
  const int w = tid >> 6;            // gate: 0=i 1=f 2=g 3=o
  const int g = blockIdx.x;          // k-slice
  const int lr = lane & 15, lk = lane >> 4;
  const int j0 = w * 1024 + g * 16;

  const unsigned short* w1p = W1 + (size_t)(j0 + lr) * 1024 + lk * 8;
  const unsigned short* ha0 = hA + lr * 1024 + lk * 8;
  const unsigned short* ha1 = hA + (16 + lr) * 1024 + lk * 8;
  const unsigned short* w2p = nullptr;
  const unsigned short* hb0 = nullptr;
  const unsigned short* hb1 = nullptr;
  if constexpr (NMAT == 2) {
    w2p = W2 + (size_t)(j0 + lr) * 1024 + lk * 8;
    hb0 = hB + lr * 1024 + lk * 8;
    hb1 = hB + (16 + lr) * 1024 + lk * 8;
  }

  f32x4 acc0 = {0.f, 0.f, 0.f, 0.f}, acc1 = {0.f, 0.f, 0.f, 0.f};
  for (int kc = 0; kc < 32; ++kc) {
    short8 bb = *(const short8*)(w1p + kc * 32);
    short8 a0 = *(const short8*)(ha0 + kc * 32);
    short8 a1 = *(const short8*)(ha1 + kc * 32);
    acc0 = MFMA16(a0, bb, acc0);
    acc1 = MFMA16(a1, bb, acc1);
    if constexpr (NMAT == 2) {
      short8 b2 = *(const short8*)(w2p + kc * 32);
      short8 c0v = *(const short8*)(hb0 + kc * 32);
      short8 c1v = *(const short8*)(hb1 + kc * 32);
      acc0 = MFMA16(c0v, b2, acc0);
      acc1 = MFMA16(c1v, b2, acc1);
    }
  }

  __shared__ float zl[4][32][16];
#pragma unroll
  for (int i = 0; i < 4; ++i) {
    zl[w][lk * 4 + i][lr] = acc0[i];
    zl[w][16 + lk * 4 + i][lr] = acc1[i];
  }
  __syncthreads();

#pragma unroll
  for (int it = 0; it < 2; ++it) {
    int idx = tid + it * 256;        // 0..511
    int b = idx >> 4, kl = idx & 15;
    int k = g * 16 + kl;
    float zi = zl[0][b][kl], zf = zl[1][b][kl], zg = zl[2][b][kl], zo = zl[3][b][kl];
    if (base) {
      const float* br = base + b * 4096;
      zi += br[k]; zf += br[1024 + k]; zg += br[2048 + k]; zo += br[3072 + k];
    }
    if (bias) {
      zi += bias[k]; zf += bias[1024 + k]; zg += bias[2048 + k]; zo += bias[3072 + k];
    }
    float co = c[b * 1024 + k];
    float ii = 1.f / (1.f + __expf(-zi));
    float ff = 1.f / (1.f + __expf(-zf));
    float gg = tanhf(zg);
    float oo = 1.f / (1.f + __expf(-zo));
    float cn = ff * co + ii * gg;
    float hn = oo * tanhf(cn);
    c[b * 1024 + k] = cn;
    h_out[b * 1024 + k] = f2bf(hn);
    if (WOUT) out_t[(size_t)b * 131072 + k] = f2bf(hn);
  }
}

// ---------------------------------------------------------------------------

extern "C" void kernel_launch(void* const* d_in, const int* in_sizes, int n_in,
                              void* d_out, int out_size, void* d_ws, size_t ws_size,
                              hipStream_t stream) {
  const int*   x      = (const int*)d_in[0];
  const float* hidden = (const float*)d_in[1];
  const float* cell   = (const float*)d_in[2];
  const int*   target = (const int*)d_in[3];
  const float* emb    = (const float*)d_in[5];
  const float* w_ih   = (const float*)d_in[6];
  const float* w_hh   = (const float*)d_in[7];
  const float* b_ih   = (const float*)d_in[8];
  const float* b_hh   = (const float*)d_in[9];
  float* out = (float*)d_out;
  char* ws = (char*)d_ws;

  // ws layout (bytes)
  unsigned short* emb_bf = (unsigned short*)(ws);                  // 65,536,000
  unsigned short* wih_bf = (unsigned short*)(ws + 65536000);       // 16,777,216
  unsigned short* whh_bf = (unsigned short*)(ws + 82313216);       // 16,777,216
  float*          bsum   = (float*)(ws + 99090432);                // 32,768
  unsigned short* h0b[2] = {(unsigned short*)(ws + 99123200),
                            (unsigned short*)(ws + 99188736)};
  unsigned short* h1b[2] = {(unsigned short*)(ws + 99254272),
                            (unsigned short*)(ws + 99319808)};
  float*          c0     = (float*)(ws + 99385344);                // 131,072
  float*          c1     = (float*)(ws + 99516416);                // 131,072 (contig after c0)
  unsigned short* outb   = (unsigned short*)(ws + 99647488);       // 8,388,608
  // Zx0 (67 MB) + x_seq (8.4 MB) live in d_out's dead space: proj overwrites
  // d_out only after all step kernels have consumed Zx0/x_seq.
  float*          zx0  = (float*)((char*)d_out);                   // 67,108,864
  unsigned short* xseq = (unsigned short*)((char*)d_out + 67108864); // 8,388,608

  cvt_bf16_k<<<2048, 256, 0, stream>>>(emb, emb_bf, 32768000 / 4);
  cvt_bf16_k<<<2048, 256, 0, stream>>>(w_ih, wih_bf, 8388608 / 4);
  cvt_bf16_k<<<2048, 256, 0, stream>>>(w_hh, whh_bf, 8388608 / 4);
  cvt_bf16_k<<<32, 256, 0, stream>>>(hidden, h0b[0], 32768 / 4);
  cvt_bf16_k<<<32, 256, 0, stream>>>(hidden + 32768, h1b[0], 32768 / 4);
  copy_f32_k<<<64, 256, 0, stream>>>(cell, c0, 65536 / 4);   // c0 and c1 contiguous
  bias_sum_k<<<32, 256, 0, stream>>>(b_ih, b_hh, bsum, 8192);
  embed_k<<<4096, 256, 0, stream>>>(x, target, emb, xseq);

  // Zx0 = x_seq @ w_ih[0]^T + bsum0   [4096 x 4096], K=1024
  gemm_bf16_k<<<dim3(32, 32), 256, 0, stream>>>(xseq, wih_bf, zx0, bsum, 4096);

  for (int t = 0; t < 128; ++t) {
    int pi = t & 1, po = pi ^ 1;
    lstm_step_k<1, 0><<<64, 256, 0, stream>>>(
        h0b[pi], whh_bf, nullptr, nullptr,
        zx0 + (size_t)t * 32 * 4096, nullptr, c0, h0b[po], nullptr);
    lstm_step_k<2, 1><<<64, 256, 0, stream>>>(
        h0b[po], wih_bf + (size_t)4096 * 1024, h1b[pi], whh_bf + (size_t)4096 * 1024,
        nullptr, bsum + 4096, c1, h1b[po], outb + (size_t)t * 1024);
  }

  // out = outbuf @ emb_bf^T   [4096 x 32000], K=1024
  gemm_bf16_k<<<dim3(250, 32), 256, 0, stream>>>(outb, emb_bf, out, nullptr, 32000);
}

// Round 3
// 4989.838 us; speedup vs baseline: 1.3701x; 1.3701x over previous
//
#include <hip/hip_runtime.h>
#include <stdint.h>

// ---------------------------------------------------------------------------
// DecoderLSTM: B=32, S=128, H=1024, L=2, V=32000, teacher forcing (tf=1)
//
//   1. cvt weights/emb -> bf16, bsum = b_ih+b_hh, h/c inits.
//   2. embed tokens -> x_seq bf16 [4096][1024] (rows t*32+b)     (in d_out)
//   3. Zx0 = x_seq @ w_ih[0]^T + bsum0  (MFMA GEMM, f32)         (in d_out)
//   4. ONE persistent kernel (plain launch, hand-rolled grid barrier) runs
//      all 128 steps:
//        - 192 WGs (<= 256 CUs, 1 WG/CU at launch_bounds(256,1) => all
//          co-resident): 64 layer0-WGs (16 units), 128 layer1-WGs (8 units).
//        - weights register-resident as MFMA B-frags; cell in registers;
//          h broadcast via global + device-scope barrier.
//        - layer1 pipelined one step behind layer0 -> 1 barrier/iter, 129.
//   5. out = outb @ emb_bf^T (MFMA GEMM, M=4096, N=32000, K=1024)
// ---------------------------------------------------------------------------

typedef __attribute__((ext_vector_type(8))) short short8;
typedef __attribute__((ext_vector_type(4))) float f32x4;

#define MFMA16(a, b, c) __builtin_amdgcn_mfma_f32_16x16x32_bf16((a), (b), (c), 0, 0, 0)

__device__ __forceinline__ unsigned short f2bf(float f) {
  union { float f; unsigned int u; } v; v.f = f;
  unsigned int u = v.u;
  return (unsigned short)((u + 0x7fffu + ((u >> 16) & 1u)) >> 16);
}

// device-scope sense-free grid barrier: bar monotonically counts arrivals.
// Caller passes target = iter_count * gridDim.x.
__device__ __forceinline__ void gbar(unsigned int* bar, unsigned int target) {
  __syncthreads();
  if (threadIdx.x == 0) {
    __threadfence();   // agent release: write back dirty L2 (buffer_wbl2)
    __hip_atomic_fetch_add(bar, 1u, __ATOMIC_RELAXED, __HIP_MEMORY_SCOPE_AGENT);
    while (__hip_atomic_load(bar, __ATOMIC_RELAXED, __HIP_MEMORY_SCOPE_AGENT) < target) {
      __builtin_amdgcn_s_sleep(1);
    }
    __threadfence();   // agent acquire: invalidate L2 (buffer_inv)
  }
  __syncthreads();
}

// ---- conversion / small kernels -------------------------------------------

__global__ void cvt_bf16_k(const float* __restrict__ s, unsigned short* __restrict__ d, int n4) {
  int i = blockIdx.x * blockDim.x + threadIdx.x;
  int st = gridDim.x * blockDim.x;
  for (; i < n4; i += st) {
    float4 v = ((const float4*)s)[i];
    ushort4 o;
    o.x = f2bf(v.x); o.y = f2bf(v.y); o.z = f2bf(v.z); o.w = f2bf(v.w);
    ((ushort4*)d)[i] = o;
  }
}

__global__ void bias_sum_k(const float* __restrict__ a, const float* __restrict__ b,
                           float* __restrict__ o, int n) {
  int i = blockIdx.x * blockDim.x + threadIdx.x;
  if (i < n) o[i] = a[i] + b[i];
}

__global__ void embed_k(const int* __restrict__ x, const int* __restrict__ tgt,
                        const float* __restrict__ emb, unsigned short* __restrict__ xseq) {
  int row = blockIdx.x;          // t*32 + b
  int t = row >> 5, b = row & 31;
  int tok = (t == 0) ? x[b] : tgt[b * 128 + t];
  const float4* e = (const float4*)(emb + (size_t)tok * 1024);
  ushort4* o = (ushort4*)(xseq + (size_t)row * 1024);
  int i = threadIdx.x;
  float4 v = e[i];
  ushort4 u;
  u.x = f2bf(v.x); u.y = f2bf(v.y); u.z = f2bf(v.z); u.w = f2bf(v.w);
  o[i] = u;
}

// ---- bf16 MFMA GEMM: C[M][N] = A[M][K] * B[N][K]^T (+bias[col]) -----------
// (verified in round 1)

__global__ __launch_bounds__(256, 2) void gemm_bf16_k(
    const unsigned short* __restrict__ A, const unsigned short* __restrict__ B,
    float* __restrict__ C, const float* __restrict__ bias, int N) {
  __shared__ __align__(16) unsigned short As[128 * 64];
  __shared__ __align__(16) unsigned short Bs[128 * 64];
  const int tid = threadIdx.x;
  const int lane = tid & 63;
  const int w = tid >> 6;
  const int wm = w >> 1, wn = w & 1;
  const int mBase = blockIdx.y * 128;
  const int nBase = blockIdx.x * 128;
  const int lr = lane & 15, lk = lane >> 4;
  const int K = 1024;

  f32x4 acc[4][4];
#pragma unroll
  for (int i = 0; i < 4; ++i)
#pragma unroll
    for (int j = 0; j < 4; ++j) acc[i][j] = (f32x4){0.f, 0.f, 0.f, 0.f};

  for (int kt = 0; kt < K / 64; ++kt) {
    int4 va[4], vb[4];
#pragma unroll
    for (int r = 0; r < 4; ++r) {
      int q = r * 256 + tid;
      int row = q >> 3, c = q & 7;
      va[r] = *(const int4*)(A + (size_t)(mBase + row) * K + kt * 64 + c * 8);
      vb[r] = *(const int4*)(B + (size_t)(nBase + row) * K + kt * 64 + c * 8);
    }
    __syncthreads();
#pragma unroll
    for (int r = 0; r < 4; ++r) {
      int q = r * 256 + tid;
      int row = q >> 3, c = q & 7;
      int cs = c ^ (row & 7);
      *(int4*)&As[row * 64 + cs * 8] = va[r];
      *(int4*)&Bs[row * 64 + cs * 8] = vb[r];
    }
    __syncthreads();
#pragma unroll
    for (int ks = 0; ks < 2; ++ks) {
      short8 a[4], b[4];
#pragma unroll
      for (int mf = 0; mf < 4; ++mf) {
        int row = wm * 64 + mf * 16 + lr;
        int cc = (ks * 4 + lk) ^ (row & 7);
        a[mf] = *(const short8*)&As[row * 64 + cc * 8];
      }
#pragma unroll
      for (int nf = 0; nf < 4; ++nf) {
        int row = wn * 64 + nf * 16 + lr;
        int cc = (ks * 4 + lk) ^ (row & 7);
        b[nf] = *(const short8*)&Bs[row * 64 + cc * 8];
      }
#pragma unroll
      for (int mf = 0; mf < 4; ++mf)
#pragma unroll
        for (int nf = 0; nf < 4; ++nf)
          acc[mf][nf] = MFMA16(a[mf], b[nf], acc[mf][nf]);
    }
  }

#pragma unroll
  for (int mf = 0; mf < 4; ++mf) {
#pragma unroll
    for (int nf = 0; nf < 4; ++nf) {
      int col = nBase + wn * 64 + nf * 16 + lr;
      float bv = bias ? bias[col] : 0.f;
#pragma unroll
      for (int i = 0; i < 4; ++i) {
        int row = mBase + wm * 64 + mf * 16 + lk * 4 + i;
        C[(size_t)row * N + col] = acc[mf][nf][i] + bv;
      }
    }
  }
}

// ---- persistent recurrence kernel -----------------------------------------
// 192 WGs x 256 thr, plain launch, all co-resident (1 WG/CU).
// Blocks 0..63: layer0 (16 units each). Blocks 64..191: layer1 (8 units).
// Iteration i: layer0 computes h0[i+1] (i<128); layer1 computes t=i-1 (i>=1).

struct PParams {
  const float* zx0;             // [128][32][4096]
  const unsigned short* whh0;   // [4096][1024] bf16
  const unsigned short* wih1;   // [4096][1024] bf16
  const unsigned short* whh1;   // [4096][1024] bf16
  const float* bsum1;           // [4096]
  const float* cell;            // [2][32][1024] f32
  unsigned short* h0hist;       // [129][32][1024] bf16
  const unsigned short* h1init; // [32][1024] bf16
  unsigned short* outb;         // [32][128][1024] bf16
  unsigned int* bar;            // grid barrier counter (pre-zeroed)
};

__global__ __launch_bounds__(256, 1) void lstm_persist_k(PParams P) {
  const int tid = threadIdx.x;
  const int lane = tid & 63;
  const int w = tid >> 6;
  const int lr = lane & 15, lkk = lane >> 4;
  const unsigned int NB = gridDim.x;

  __shared__ float zbuf[32][68];

  if (blockIdx.x < 64) {
    // ---------------- layer 0: units u0..u0+15 ----------------
    const int u0 = blockIdx.x * 16;
    const int m = w >> 1;
    const int p = w & 1;
    const int g0 = p * 2, g1 = p * 2 + 1;

    short8 bw0[32], bw1[32];
    {
      const unsigned short* r0 = P.whh0 + (size_t)(g0 * 1024 + u0 + lr) * 1024 + lkk * 8;
      const unsigned short* r1 = P.whh0 + (size_t)(g1 * 1024 + u0 + lr) * 1024 + lkk * 8;
#pragma unroll
      for (int ks = 0; ks < 32; ++ks) {
        bw0[ks] = *(const short8*)(r0 + ks * 32);
        bw1[ks] = *(const short8*)(r1 + ks * 32);
      }
    }
    float creg[2];
    int fb[2], fj[2];
#pragma unroll
    for (int q = 0; q < 2; ++q) {
      int idx = tid + q * 256;
      fb[q] = idx >> 4; fj[q] = idx & 15;
      creg[q] = P.cell[fb[q] * 1024 + u0 + fj[q]];
    }

    for (int i = 0; i < 129; ++i) {
      if (i < 128) {
        f32x4 acc0 = {0.f, 0.f, 0.f, 0.f}, acc1 = {0.f, 0.f, 0.f, 0.f};
        const unsigned short* ap =
            P.h0hist + (size_t)i * 32768 + (size_t)(m * 16 + lr) * 1024 + lkk * 8;
#pragma unroll
        for (int g4 = 0; g4 < 4; ++g4) {
          short8 a[8];
#pragma unroll
          for (int q = 0; q < 8; ++q) a[q] = *(const short8*)(ap + (g4 * 8 + q) * 32);
#pragma unroll
          for (int q = 0; q < 8; ++q) {
            acc0 = MFMA16(a[q], bw0[g4 * 8 + q], acc0);
            acc1 = MFMA16(a[q], bw1[g4 * 8 + q], acc1);
          }
        }
#pragma unroll
        for (int j = 0; j < 4; ++j) {
          zbuf[m * 16 + lkk * 4 + j][g0 * 16 + lr] = acc0[j];
          zbuf[m * 16 + lkk * 4 + j][g1 * 16 + lr] = acc1[j];
        }
        __syncthreads();
        const float* base = P.zx0 + (size_t)i * 131072;
#pragma unroll
        for (int q = 0; q < 2; ++q) {
          int b = fb[q], j = fj[q];
          const float* br = base + b * 4096;
          float zi = zbuf[b][j]      + br[u0 + j];
          float zf = zbuf[b][16 + j] + br[1024 + u0 + j];
          float zg = zbuf[b][32 + j] + br[2048 + u0 + j];
          float zo = zbuf[b][48 + j] + br[3072 + u0 + j];
          float ii = 1.f / (1.f + __expf(-zi));
          float ff = 1.f / (1.f + __expf(-zf));
          float gg = tanhf(zg);
          float oo = 1.f / (1.f + __expf(-zo));
          float cn = ff * creg[q] + ii * gg;
          creg[q] = cn;
          float hn = oo * tanhf(cn);
          P.h0hist[(size_t)(i + 1) * 32768 + b * 1024 + u0 + j] = f2bf(hn);
        }
      }
      gbar(P.bar, (unsigned)(i + 1) * NB);
    }
  } else {
    // ---------------- layer 1: units u0..u0+7 ----------------
    const int u0 = (blockIdx.x - 64) * 8;
    const int m = w >> 1;
    const int n = w & 1;
    const int gA = (n * 16 + lr) >> 3;
    const int un = (n * 16 + lr) & 7;
    const size_t R = (size_t)(gA * 1024 + u0 + un) * 1024;

    short8 bwi[32], bwh[32];
#pragma unroll
    for (int ks = 0; ks < 32; ++ks) {
      bwi[ks] = *(const short8*)(P.wih1 + R + ks * 32 + lkk * 8);
      bwh[ks] = *(const short8*)(P.whh1 + R + ks * 32 + lkk * 8);
    }
    const int fbb = tid >> 3, fjj = tid & 7;
    float creg = P.cell[32768 + fbb * 1024 + u0 + fjj];
    float breg[4];
#pragma unroll
    for (int g = 0; g < 4; ++g) breg[g] = P.bsum1[g * 1024 + u0 + fjj];

    for (int i = 0; i < 129; ++i) {
      if (i >= 1) {
        f32x4 accA = {0.f, 0.f, 0.f, 0.f}, accB = {0.f, 0.f, 0.f, 0.f};
        const unsigned short* a0p =
            P.h0hist + (size_t)i * 32768 + (size_t)(m * 16 + lr) * 1024 + lkk * 8;
        size_t h1s = (i == 1) ? 1024 : 131072;
        const unsigned short* h1b =
            (i == 1) ? P.h1init : (P.outb + (size_t)(i - 2) * 1024);
        const unsigned short* a1p = h1b + (size_t)(m * 16 + lr) * h1s + lkk * 8;
#pragma unroll
        for (int g4 = 0; g4 < 4; ++g4) {
          short8 a0[8], a1[8];
#pragma unroll
          for (int q = 0; q < 8; ++q) {
            a0[q] = *(const short8*)(a0p + (g4 * 8 + q) * 32);
            a1[q] = *(const short8*)(a1p + (g4 * 8 + q) * 32);
          }
#pragma unroll
          for (int q = 0; q < 8; ++q) {
            accA = MFMA16(a0[q], bwi[g4 * 8 + q], accA);
            accB = MFMA16(a1[q], bwh[g4 * 8 + q], accB);
          }
        }
        f32x4 acc = accA + accB;
#pragma unroll
        for (int j = 0; j < 4; ++j)
          zbuf[m * 16 + lkk * 4 + j][n * 16 + lr] = acc[j];
        __syncthreads();
        {
          int b = fbb, j = fjj;
          float zi = zbuf[b][j]      + breg[0];
          float zf = zbuf[b][8 + j]  + breg[1];
          float zg = zbuf[b][16 + j] + breg[2];
          float zo = zbuf[b][24 + j] + breg[3];
          float ii = 1.f / (1.f + __expf(-zi));
          float ff = 1.f / (1.f + __expf(-zf));
          float gg = tanhf(zg);
          float oo = 1.f / (1.f + __expf(-zo));
          float cn = ff * creg + ii * gg;
          creg = cn;
          float hn = oo * tanhf(cn);
          P.outb[(size_t)b * 131072 + (size_t)(i - 1) * 1024 + u0 + j] = f2bf(hn);
        }
      }
      gbar(P.bar, (unsigned)(i + 1) * NB);
    }
  }
}

// ---------------------------------------------------------------------------

extern "C" void kernel_launch(void* const* d_in, const int* in_sizes, int n_in,
                              void* d_out, int out_size, void* d_ws, size_t ws_size,
                              hipStream_t stream) {
  const int*   x      = (const int*)d_in[0];
  const float* hidden = (const float*)d_in[1];
  const float* cell   = (const float*)d_in[2];
  const int*   target = (const int*)d_in[3];
  const float* emb    = (const float*)d_in[5];
  const float* w_ih   = (const float*)d_in[6];
  const float* w_hh   = (const float*)d_in[7];
  const float* b_ih   = (const float*)d_in[8];
  const float* b_hh   = (const float*)d_in[9];
  float* out = (float*)d_out;
  char* ws = (char*)d_ws;

  // ws layout (bytes)
  unsigned short* emb_bf  = (unsigned short*)(ws);                 // 65,536,000
  unsigned short* wih0_bf = (unsigned short*)(ws + 65536000);      //  8,388,608
  unsigned short* whh_bf  = (unsigned short*)(ws + 73924608);      // 16,777,216 (both layers)
  unsigned short* wih1_bf = (unsigned short*)(ws + 90701824);      //  8,388,608
  float*          bsum    = (float*)(ws + 99090432);               //     32,768
  unsigned short* outb    = (unsigned short*)(ws + 99123200);      //  8,388,608
  unsigned int*   bar     = (unsigned int*)(ws + 107511808);       //         64
  // Large transients in d_out's dead space (proj GEMM overwrites last):
  float*          zx0    = (float*)((char*)d_out);                         // 67,108,864
  unsigned short* xseq   = (unsigned short*)((char*)d_out + 67108864);     //  8,388,608
  unsigned short* h0hist = (unsigned short*)((char*)d_out + 75497472);     //  8,454,144
  unsigned short* h1init = (unsigned short*)((char*)d_out + 83951616);     //     65,536

  hipMemsetAsync(bar, 0, 64, stream);
  cvt_bf16_k<<<2048, 256, 0, stream>>>(emb, emb_bf, 8192000);
  cvt_bf16_k<<<1024, 256, 0, stream>>>(w_ih, wih0_bf, 1048576);
  cvt_bf16_k<<<2048, 256, 0, stream>>>(w_hh, whh_bf, 2097152);
  cvt_bf16_k<<<1024, 256, 0, stream>>>(w_ih + 4194304, wih1_bf, 1048576);
  cvt_bf16_k<<<32, 256, 0, stream>>>(hidden, h0hist, 8192);          // h0hist[0]
  cvt_bf16_k<<<32, 256, 0, stream>>>(hidden + 32768, h1init, 8192);
  bias_sum_k<<<32, 256, 0, stream>>>(b_ih, b_hh, bsum, 8192);
  embed_k<<<4096, 256, 0, stream>>>(x, target, emb, xseq);

  // Zx0 = x_seq @ w_ih[0]^T + bsum0   [4096 x 4096]
  gemm_bf16_k<<<dim3(32, 32), 256, 0, stream>>>(xseq, wih0_bf, zx0, bsum, 4096);

  // persistent recurrence: 192 WGs, hand-rolled grid barrier
  PParams pp;
  pp.zx0 = zx0;
  pp.whh0 = whh_bf;
  pp.wih1 = wih1_bf;
  pp.whh1 = whh_bf + 4194304;
  pp.bsum1 = bsum + 4096;
  pp.cell = cell;
  pp.h0hist = h0hist;
  pp.h1init = h1init;
  pp.outb = outb;
  pp.bar = bar;
  lstm_persist_k<<<192, 256, 0, stream>>>(pp);

  // out = outb @ emb_bf^T   [4096 x 32000]
  gemm_bf16_k<<<dim3(250, 32), 256, 0, stream>>>(outb, emb_bf, out, nullptr, 32000);
}

// Round 4
// 4299.099 us; speedup vs baseline: 1.5903x; 1.1607x over previous
//
#include <hip/hip_runtime.h>
#include <stdint.h>

// ---------------------------------------------------------------------------
// DecoderLSTM: B=32, S=128, H=1024, L=2, V=32000, teacher forcing (tf=1)
//
//   1. cvt weights/emb -> bf16, bsum = b_ih+b_hh, h/c inits.
//   2. embed tokens -> x_seq bf16 [4096][1024] (rows t*32+b)     (in d_out)
//   3. Zx0 = x_seq @ w_ih[0]^T + bsum0  (MFMA GEMM, f32)         (in d_out)
//   4. ONE persistent kernel (plain launch, two-level grid barrier) runs all
//      128 steps: 64 layer0-WGs (16 units), 128 layer1-WGs (8 units);
//      weights register-resident; layer1 lags one step -> 1 barrier/iter.
//   5. out = outb @ emb_bf^T (MFMA GEMM, M=4096, N=32000, K=1024)
// ---------------------------------------------------------------------------

typedef __attribute__((ext_vector_type(8))) short short8;
typedef __attribute__((ext_vector_type(4))) float f32x4;

#define MFMA16(a, b, c) __builtin_amdgcn_mfma_f32_16x16x32_bf16((a), (b), (c), 0, 0, 0)

__device__ __forceinline__ unsigned short f2bf(float f) {
  union { float f; unsigned int u; } v; v.f = f;
  unsigned int u = v.u;
  return (unsigned short)((u + 0x7fffu + ((u >> 16) & 1u)) >> 16);
}

// ---- two-level grid barrier ------------------------------------------------
// arr[g*256]: per-group arrival counters (8 groups of 24 WGs, 1KB apart).
// epoch: broadcast word. Master = block 0: lanes 0..7 poll the 8 counters,
// thread 0 bumps epoch; everyone else polls epoch only. Monotonic counters
// (pre-zeroed per call) -> graph-replay safe. One fence pair per WG:
// __syncthreads() drains all threads' stores to L2 (compiler emits
// vmcnt(0) before s_barrier), thread0's release fence (wbl2) makes them
// device-visible, thread0's acquire fence (buffer_inv: CU-L1 + XCD-L2
// wide) covers the whole WG before the closing __syncthreads().
__device__ __forceinline__ void gbar2(unsigned* arr, unsigned* epoch,
                                      unsigned it /*1-based*/, int grp,
                                      bool masterBlk) {
  __syncthreads();
  if (masterBlk) {
    if (threadIdx.x == 0) {
      __threadfence();
      __hip_atomic_fetch_add(&arr[grp * 256], 1u, __ATOMIC_RELAXED,
                             __HIP_MEMORY_SCOPE_AGENT);
    }
    if (threadIdx.x < 8) {
      while (__hip_atomic_load(&arr[threadIdx.x * 256], __ATOMIC_RELAXED,
                               __HIP_MEMORY_SCOPE_AGENT) < it * 24u) {
        __builtin_amdgcn_s_sleep(1);
      }
    }
    __syncthreads();
    if (threadIdx.x == 0) {
      __hip_atomic_fetch_add(epoch, 1u, __ATOMIC_RELAXED,
                             __HIP_MEMORY_SCOPE_AGENT);
      __threadfence();
    }
  } else {
    if (threadIdx.x == 0) {
      __threadfence();
      __hip_atomic_fetch_add(&arr[grp * 256], 1u, __ATOMIC_RELAXED,
                             __HIP_MEMORY_SCOPE_AGENT);
      while (__hip_atomic_load(epoch, __ATOMIC_RELAXED,
                               __HIP_MEMORY_SCOPE_AGENT) < it) {
        __builtin_amdgcn_s_sleep(2);
      }
      __threadfence();
    }
  }
  __syncthreads();
}

// ---- conversion / small kernels -------------------------------------------

__global__ void cvt_bf16_k(const float* __restrict__ s, unsigned short* __restrict__ d, int n4) {
  int i = blockIdx.x * blockDim.x + threadIdx.x;
  int st = gridDim.x * blockDim.x;
  for (; i < n4; i += st) {
    float4 v = ((const float4*)s)[i];
    ushort4 o;
    o.x = f2bf(v.x); o.y = f2bf(v.y); o.z = f2bf(v.z); o.w = f2bf(v.w);
    ((ushort4*)d)[i] = o;
  }
}

__global__ void bias_sum_k(const float* __restrict__ a, const float* __restrict__ b,
                           float* __restrict__ o, int n) {
  int i = blockIdx.x * blockDim.x + threadIdx.x;
  if (i < n) o[i] = a[i] + b[i];
}

__global__ void embed_k(const int* __restrict__ x, const int* __restrict__ tgt,
                        const float* __restrict__ emb, unsigned short* __restrict__ xseq) {
  int row = blockIdx.x;          // t*32 + b
  int t = row >> 5, b = row & 31;
  int tok = (t == 0) ? x[b] : tgt[b * 128 + t];
  const float4* e = (const float4*)(emb + (size_t)tok * 1024);
  ushort4* o = (ushort4*)(xseq + (size_t)row * 1024);
  int i = threadIdx.x;
  float4 v = e[i];
  ushort4 u;
  u.x = f2bf(v.x); u.y = f2bf(v.y); u.z = f2bf(v.z); u.w = f2bf(v.w);
  o[i] = u;
}

// ---- bf16 MFMA GEMM: C[M][N] = A[M][K] * B[N][K]^T (+bias[col]) -----------
// (verified in round 1; unchanged this round)

__global__ __launch_bounds__(256, 2) void gemm_bf16_k(
    const unsigned short* __restrict__ A, const unsigned short* __restrict__ B,
    float* __restrict__ C, const float* __restrict__ bias, int N) {
  __shared__ __align__(16) unsigned short As[128 * 64];
  __shared__ __align__(16) unsigned short Bs[128 * 64];
  const int tid = threadIdx.x;
  const int lane = tid & 63;
  const int w = tid >> 6;
  const int wm = w >> 1, wn = w & 1;
  const int mBase = blockIdx.y * 128;
  const int nBase = blockIdx.x * 128;
  const int lr = lane & 15, lk = lane >> 4;
  const int K = 1024;

  f32x4 acc[4][4];
#pragma unroll
  for (int i = 0; i < 4; ++i)
#pragma unroll
    for (int j = 0; j < 4; ++j) acc[i][j] = (f32x4){0.f, 0.f, 0.f, 0.f};

  for (int kt = 0; kt < K / 64; ++kt) {
    int4 va[4], vb[4];
#pragma unroll
    for (int r = 0; r < 4; ++r) {
      int q = r * 256 + tid;
      int row = q >> 3, c = q & 7;
      va[r] = *(const int4*)(A + (size_t)(mBase + row) * K + kt * 64 + c * 8);
      vb[r] = *(const int4*)(B + (size_t)(nBase + row) * K + kt * 64 + c * 8);
    }
    __syncthreads();
#pragma unroll
    for (int r = 0; r < 4; ++r) {
      int q = r * 256 + tid;
      int row = q >> 3, c = q & 7;
      int cs = c ^ (row & 7);
      *(int4*)&As[row * 64 + cs * 8] = va[r];
      *(int4*)&Bs[row * 64 + cs * 8] = vb[r];
    }
    __syncthreads();
#pragma unroll
    for (int ks = 0; ks < 2; ++ks) {
      short8 a[4], b[4];
#pragma unroll
      for (int mf = 0; mf < 4; ++mf) {
        int row = wm * 64 + mf * 16 + lr;
        int cc = (ks * 4 + lk) ^ (row & 7);
        a[mf] = *(const short8*)&As[row * 64 + cc * 8];
      }
#pragma unroll
      for (int nf = 0; nf < 4; ++nf) {
        int row = wn * 64 + nf * 16 + lr;
        int cc = (ks * 4 + lk) ^ (row & 7);
        b[nf] = *(const short8*)&Bs[row * 64 + cc * 8];
      }
#pragma unroll
      for (int mf = 0; mf < 4; ++mf)
#pragma unroll
        for (int nf = 0; nf < 4; ++nf)
          acc[mf][nf] = MFMA16(a[mf], b[nf], acc[mf][nf]);
    }
  }

#pragma unroll
  for (int mf = 0; mf < 4; ++mf) {
#pragma unroll
    for (int nf = 0; nf < 4; ++nf) {
      int col = nBase + wn * 64 + nf * 16 + lr;
      float bv = bias ? bias[col] : 0.f;
#pragma unroll
      for (int i = 0; i < 4; ++i) {
        int row = mBase + wm * 64 + mf * 16 + lk * 4 + i;
        C[(size_t)row * N + col] = acc[mf][nf][i] + bv;
      }
    }
  }
}

// ---- persistent recurrence kernel -----------------------------------------
// 192 WGs x 256 thr, plain launch, all co-resident (1 WG/CU).
// Blocks 0..63: layer0 (16 units each). Blocks 64..191: layer1 (8 units).
// Iteration i: layer0 computes h0[i+1] (i<128); layer1 computes t=i-1 (i>=1).

struct PParams {
  const float* zx0;             // [128][32][4096]
  const unsigned short* whh0;   // [4096][1024] bf16
  const unsigned short* wih1;   // [4096][1024] bf16
  const unsigned short* whh1;   // [4096][1024] bf16
  const float* bsum1;           // [4096]
  const float* cell;            // [2][32][1024] f32
  unsigned short* h0hist;       // [129][32][1024] bf16
  const unsigned short* h1init; // [32][1024] bf16
  unsigned short* outb;         // [32][128][1024] bf16
  unsigned int* arr;            // 8 arrival counters, 1KB apart (pre-zeroed)
  unsigned int* epoch;          // broadcast epoch word (pre-zeroed)
};

__global__ __launch_bounds__(256, 1) void lstm_persist_k(PParams P) {
  const int tid = threadIdx.x;
  const int lane = tid & 63;
  const int w = tid >> 6;
  const int lr = lane & 15, lkk = lane >> 4;
  const int grp = blockIdx.x & 7;
  const bool masterBlk = (blockIdx.x == 0);

  __shared__ float zbuf[32][68];

  if (blockIdx.x < 64) {
    // ---------------- layer 0: units u0..u0+15 ----------------
    const int u0 = blockIdx.x * 16;
    const int m = w >> 1;
    const int p = w & 1;
    const int g0 = p * 2, g1 = p * 2 + 1;

    short8 bw0[32], bw1[32];
    {
      const unsigned short* r0 = P.whh0 + (size_t)(g0 * 1024 + u0 + lr) * 1024 + lkk * 8;
      const unsigned short* r1 = P.whh0 + (size_t)(g1 * 1024 + u0 + lr) * 1024 + lkk * 8;
#pragma unroll
      for (int ks = 0; ks < 32; ++ks) {
        bw0[ks] = *(const short8*)(r0 + ks * 32);
        bw1[ks] = *(const short8*)(r1 + ks * 32);
      }
    }
    float creg[2];
    int fb[2], fj[2];
#pragma unroll
    for (int q = 0; q < 2; ++q) {
      int idx = tid + q * 256;
      fb[q] = idx >> 4; fj[q] = idx & 15;
      creg[q] = P.cell[fb[q] * 1024 + u0 + fj[q]];
    }

    for (int i = 0; i < 129; ++i) {
      if (i < 128) {
        // hoist zx0 loads: HBM latency hides under the MFMA block below
        float zr[2][4];
#pragma unroll
        for (int q = 0; q < 2; ++q) {
          const float* br = P.zx0 + (size_t)i * 131072 + fb[q] * 4096 + u0 + fj[q];
          zr[q][0] = br[0]; zr[q][1] = br[1024]; zr[q][2] = br[2048]; zr[q][3] = br[3072];
        }
        f32x4 acc0 = {0.f, 0.f, 0.f, 0.f}, acc1 = {0.f, 0.f, 0.f, 0.f};
        const unsigned short* ap =
            P.h0hist + (size_t)i * 32768 + (size_t)(m * 16 + lr) * 1024 + lkk * 8;
#pragma unroll
        for (int g4 = 0; g4 < 4; ++g4) {
          short8 a[8];
#pragma unroll
          for (int q = 0; q < 8; ++q) a[q] = *(const short8*)(ap + (g4 * 8 + q) * 32);
#pragma unroll
          for (int q = 0; q < 8; ++q) {
            acc0 = MFMA16(a[q], bw0[g4 * 8 + q], acc0);
            acc1 = MFMA16(a[q], bw1[g4 * 8 + q], acc1);
          }
        }
#pragma unroll
        for (int j = 0; j < 4; ++j) {
          zbuf[m * 16 + lkk * 4 + j][g0 * 16 + lr] = acc0[j];
          zbuf[m * 16 + lkk * 4 + j][g1 * 16 + lr] = acc1[j];
        }
        __syncthreads();
#pragma unroll
        for (int q = 0; q < 2; ++q) {
          int b = fb[q], j = fj[q];
          float zi = zbuf[b][j]      + zr[q][0];
          float zf = zbuf[b][16 + j] + zr[q][1];
          float zg = zbuf[b][32 + j] + zr[q][2];
          float zo = zbuf[b][48 + j] + zr[q][3];
          float ii = 1.f / (1.f + __expf(-zi));
          float ff = 1.f / (1.f + __expf(-zf));
          float gg = tanhf(zg);
          float oo = 1.f / (1.f + __expf(-zo));
          float cn = ff * creg[q] + ii * gg;
          creg[q] = cn;
          float hn = oo * tanhf(cn);
          P.h0hist[(size_t)(i + 1) * 32768 + b * 1024 + u0 + j] = f2bf(hn);
        }
      }
      if (i < 128) gbar2(P.arr, P.epoch, (unsigned)(i + 1), grp, masterBlk);
    }
  } else {
    // ---------------- layer 1: units u0..u0+7 ----------------
    const int u0 = (blockIdx.x - 64) * 8;
    const int m = w >> 1;
    const int n = w & 1;
    const int gA = (n * 16 + lr) >> 3;
    const int un = (n * 16 + lr) & 7;
    const size_t R = (size_t)(gA * 1024 + u0 + un) * 1024;

    short8 bwi[32], bwh[32];
#pragma unroll
    for (int ks = 0; ks < 32; ++ks) {
      bwi[ks] = *(const short8*)(P.wih1 + R + ks * 32 + lkk * 8);
      bwh[ks] = *(const short8*)(P.whh1 + R + ks * 32 + lkk * 8);
    }
    const int fbb = tid >> 3, fjj = tid & 7;
    float creg = P.cell[32768 + fbb * 1024 + u0 + fjj];
    float breg[4];
#pragma unroll
    for (int g = 0; g < 4; ++g) breg[g] = P.bsum1[g * 1024 + u0 + fjj];

    for (int i = 0; i < 129; ++i) {
      if (i >= 1) {
        f32x4 accA = {0.f, 0.f, 0.f, 0.f}, accB = {0.f, 0.f, 0.f, 0.f};
        const unsigned short* a0p =
            P.h0hist + (size_t)i * 32768 + (size_t)(m * 16 + lr) * 1024 + lkk * 8;
        size_t h1s = (i == 1) ? 1024 : 131072;
        const unsigned short* h1b =
            (i == 1) ? P.h1init : (P.outb + (size_t)(i - 2) * 1024);
        const unsigned short* a1p = h1b + (size_t)(m * 16 + lr) * h1s + lkk * 8;
#pragma unroll
        for (int g4 = 0; g4 < 4; ++g4) {
          short8 a0[8], a1[8];
#pragma unroll
          for (int q = 0; q < 8; ++q) {
            a0[q] = *(const short8*)(a0p + (g4 * 8 + q) * 32);
            a1[q] = *(const short8*)(a1p + (g4 * 8 + q) * 32);
          }
#pragma unroll
          for (int q = 0; q < 8; ++q) {
            accA = MFMA16(a0[q], bwi[g4 * 8 + q], accA);
            accB = MFMA16(a1[q], bwh[g4 * 8 + q], accB);
          }
        }
        f32x4 acc = accA + accB;
#pragma unroll
        for (int j = 0; j < 4; ++j)
          zbuf[m * 16 + lkk * 4 + j][n * 16 + lr] = acc[j];
        __syncthreads();
        {
          int b = fbb, j = fjj;
          float zi = zbuf[b][j]      + breg[0];
          float zf = zbuf[b][8 + j]  + breg[1];
          float zg = zbuf[b][16 + j] + breg[2];
          float zo = zbuf[b][24 + j] + breg[3];
          float ii = 1.f / (1.f + __expf(-zi));
          float ff = 1.f / (1.f + __expf(-zf));
          float gg = tanhf(zg);
          float oo = 1.f / (1.f + __expf(-zo));
          float cn = ff * creg + ii * gg;
          creg = cn;
          float hn = oo * tanhf(cn);
          P.outb[(size_t)b * 131072 + (size_t)(i - 1) * 1024 + u0 + j] = f2bf(hn);
        }
      }
      if (i < 128) gbar2(P.arr, P.epoch, (unsigned)(i + 1), grp, masterBlk);
    }
  }
}

// ---------------------------------------------------------------------------

extern "C" void kernel_launch(void* const* d_in, const int* in_sizes, int n_in,
                              void* d_out, int out_size, void* d_ws, size_t ws_size,
                              hipStream_t stream) {
  const int*   x      = (const int*)d_in[0];
  const float* hidden = (const float*)d_in[1];
  const float* cell   = (const float*)d_in[2];
  const int*   target = (const int*)d_in[3];
  const float* emb    = (const float*)d_in[5];
  const float* w_ih   = (const float*)d_in[6];
  const float* w_hh   = (const float*)d_in[7];
  const float* b_ih   = (const float*)d_in[8];
  const float* b_hh   = (const float*)d_in[9];
  float* out = (float*)d_out;
  char* ws = (char*)d_ws;

  // ws layout (bytes)
  unsigned short* emb_bf  = (unsigned short*)(ws);                 // 65,536,000
  unsigned short* wih0_bf = (unsigned short*)(ws + 65536000);      //  8,388,608
  unsigned short* whh_bf  = (unsigned short*)(ws + 73924608);      // 16,777,216 (both layers)
  unsigned short* wih1_bf = (unsigned short*)(ws + 90701824);      //  8,388,608
  float*          bsum    = (float*)(ws + 99090432);               //     32,768
  unsigned short* outb    = (unsigned short*)(ws + 99123200);      //  8,388,608
  unsigned int*   barmem  = (unsigned int*)(ws + 107511808);       //     16,384
  // Large transients in d_out's dead space (proj GEMM overwrites last):
  float*          zx0    = (float*)((char*)d_out);                         // 67,108,864
  unsigned short* xseq   = (unsigned short*)((char*)d_out + 67108864);     //  8,388,608
  unsigned short* h0hist = (unsigned short*)((char*)d_out + 75497472);     //  8,454,144
  unsigned short* h1init = (unsigned short*)((char*)d_out + 83951616);     //     65,536

  hipMemsetAsync(barmem, 0, 16384, stream);
  cvt_bf16_k<<<2048, 256, 0, stream>>>(emb, emb_bf, 8192000);
  cvt_bf16_k<<<1024, 256, 0, stream>>>(w_ih, wih0_bf, 1048576);
  cvt_bf16_k<<<2048, 256, 0, stream>>>(w_hh, whh_bf, 2097152);
  cvt_bf16_k<<<1024, 256, 0, stream>>>(w_ih + 4194304, wih1_bf, 1048576);
  cvt_bf16_k<<<32, 256, 0, stream>>>(hidden, h0hist, 8192);          // h0hist[0]
  cvt_bf16_k<<<32, 256, 0, stream>>>(hidden + 32768, h1init, 8192);
  bias_sum_k<<<32, 256, 0, stream>>>(b_ih, b_hh, bsum, 8192);
  embed_k<<<4096, 256, 0, stream>>>(x, target, emb, xseq);

  // Zx0 = x_seq @ w_ih[0]^T + bsum0   [4096 x 4096]
  gemm_bf16_k<<<dim3(32, 32), 256, 0, stream>>>(xseq, wih0_bf, zx0, bsum, 4096);

  // persistent recurrence: 192 WGs, two-level grid barrier
  PParams pp;
  pp.zx0 = zx0;
  pp.whh0 = whh_bf;
  pp.wih1 = wih1_bf;
  pp.whh1 = whh_bf + 4194304;
  pp.bsum1 = bsum + 4096;
  pp.cell = cell;
  pp.h0hist = h0hist;
  pp.h1init = h1init;
  pp.outb = outb;
  pp.arr = barmem;                 // arr[g*256], g=0..7 (1KB spacing)
  pp.epoch = barmem + 8 * 256;     // separate cacheline
  lstm_persist_k<<<192, 256, 0, stream>>>(pp);

  // out = outb @ emb_bf^T   [4096 x 32000]
  gemm_bf16_k<<<dim3(250, 32), 256, 0, stream>>>(outb, emb_bf, out, nullptr, 32000);
}